// Round 1
// baseline (458.854 us; speedup 1.0000x reference)
//
#include <hip/hip_runtime.h>

// Problem: T=2048, B=16, N=2048, binary fp32 spikes, duration=100.
// out[t,b,n] = 1 if any spike in window [t-duration+1, t], else 0.
// Streaming scan over time with "last spike time" state; time split into
// chunks of CHUNK=256 with a (duration-1)-step halo re-scan.
//
// This revision: latency-bound fix. 8B/lane float2 vector loads+stores
// (wave = 512B/instr), unroll 8 main / 4 halo so ~8 loads (4KB/wave) are
// in flight, nontemporal stores (output never re-read -> don't pollute L2).
// Grid: (64, 8) = 512 blocks = 2048 waves = 8 waves/CU.

#define T_TOTAL 2048
#define M_COLS  (16 * 2048)   // B*N, contiguous fastest axis
#define CHUNK   256           // time steps per block (halo overhead 99/256)
#define VEC     2             // columns per thread (float2)

typedef float v2f __attribute__((ext_vector_type(2)));

__global__ __launch_bounds__(256) void psp_scan_kernel(
    const float* __restrict__ x,
    const int*  __restrict__ dur_p,
    float* __restrict__ out)
{
    const int pair = blockIdx.x * blockDim.x + threadIdx.x;  // 0 .. M_COLS/2-1
    const int col  = pair * VEC;
    const int t0   = blockIdx.y * CHUNK;
    const int duration = dur_p[0];                            // uniform scalar load

    // sentinel: guarantees (t - last) >= duration for all t >= t0 until a spike
    int last0 = t0 - duration;
    int last1 = last0;

    int tstart = t0 - duration + 1;
    if (tstart < 0) tstart = 0;

    const v2f* __restrict__ xc = (const v2f*)(x + col);
    v2f* __restrict__ oc       = (v2f*)(out + col);
    const int stride = M_COLS / VEC;   // row stride in float2 units

    // Halo: recover "time of last spike" entering this chunk.
    // Independent addresses -> unroll keeps several loads in flight.
    #pragma unroll 4
    for (int t = tstart; t < t0; ++t) {
        v2f v = xc[t * stride];
        if (v.x != 0.0f) last0 = t;
        if (v.y != 0.0f) last1 = t;
    }

    // Main chunk: scan + emit. 8 x 512B wave-loads in flight per wave.
    #pragma unroll 8
    for (int t = t0; t < t0 + CHUNK; ++t) {
        v2f v = xc[t * stride];
        if (v.x != 0.0f) last0 = t;
        if (v.y != 0.0f) last1 = t;
        v2f o;
        o.x = (t - last0 < duration) ? 1.0f : 0.0f;
        o.y = (t - last1 < duration) ? 1.0f : 0.0f;
        __builtin_nontemporal_store(o, &oc[t * stride]);
    }
}

extern "C" void kernel_launch(void* const* d_in, const int* in_sizes, int n_in,
                              void* d_out, int out_size, void* d_ws, size_t ws_size,
                              hipStream_t stream) {
    const float* x     = (const float*)d_in[0];
    const int*   dur_p = (const int*)d_in[1];
    float*       out   = (float*)d_out;

    dim3 grid(M_COLS / VEC / 256, T_TOTAL / CHUNK);   // (64, 8) = 512 blocks
    dim3 block(256);
    psp_scan_kernel<<<grid, block, 0, stream>>>(x, dur_p, out);
}